// Round 3
// baseline (572.301 us; speedup 1.0000x reference)
//
#include <hip/hip_runtime.h>
#include <stdint.h>

typedef __bf16 bf16_t;
typedef bf16_t bf16x8 __attribute__((ext_vector_type(8)));
typedef float f32x16 __attribute__((ext_vector_type(16)));

#define D_DIM 4096   // K
#define O_DIM 4096   // N
#define M_DIM 16384  // M
#define THRESH 0.05f

// ---------- helpers ----------

__device__ __forceinline__ void gld16(const void* g, void* l) {
  __builtin_amdgcn_global_load_lds(
      (const __attribute__((address_space(1))) uint32_t*)(uintptr_t)g,
      (__attribute__((address_space(3))) uint32_t*)(uint32_t)(uintptr_t)l,
      16, 0, 0);
}

__device__ __forceinline__ unsigned short f2bf(float f) {  // RNE f32->bf16
  uint32_t u = __float_as_uint(f);
  u += 0x7FFFu + ((u >> 16) & 1u);
  return (unsigned short)(u >> 16);
}

__device__ __forceinline__ unsigned short tern(float v) {  // bf16 bits of {-1,0,+1}
  return (__builtin_fabsf(v) < THRESH) ? (unsigned short)0
         : (v > 0.f ? (unsigned short)0x3F80 : (unsigned short)0xBF80);
}

// ---------- pre-pass kernels (verified rounds 1-2) ----------

__global__ void k_scale_part(const float* __restrict__ w, float* __restrict__ part) {
  const int cg = blockIdx.x & 63;
  const int dz = blockIdx.x >> 6;
  const int tx = threadIdx.x & 63;
  const int ty = threadIdx.x >> 6;
  const int o = cg * 64 + tx;
  float s = 0.f;
  const float* p = w + (size_t)(dz * 512 + ty) * O_DIM + o;
  for (int i = 0; i < 128; ++i) {
    s += __builtin_fabsf(*p);
    p += 4 * O_DIM;
  }
  __shared__ float red[4][64];
  red[ty][tx] = s;
  __syncthreads();
  if (ty == 0) part[dz * O_DIM + o] = (red[0][tx] + red[1][tx]) + (red[2][tx] + red[3][tx]);
}

__global__ void k_scale_fin(const float* __restrict__ part, float* __restrict__ scale) {
  const int o = blockIdx.x * 256 + threadIdx.x;
  float s = 0.f;
#pragma unroll
  for (int z = 0; z < 8; ++z) s += part[z * O_DIM + o];
  scale[o] = s * (1.0f / 4096.0f);
}

__global__ void k_tern_t(const float* __restrict__ w, unsigned short* __restrict__ bt) {
  __shared__ __align__(16) unsigned short tile[64][68];
  const int ot = blockIdx.x & 63;
  const int dt = blockIdx.x >> 6;
  const int o0 = ot * 64, d0 = dt * 64;
  const int tx = threadIdx.x & 15, ty = threadIdx.x >> 4;
#pragma unroll
  for (int j = 0; j < 4; ++j) {
    const int r = ty + 16 * j;
    const float4 v = *(const float4*)&w[(size_t)(d0 + r) * O_DIM + o0 + tx * 4];
    ushort4 u;
    u.x = tern(v.x); u.y = tern(v.y); u.z = tern(v.z); u.w = tern(v.w);
    *(ushort4*)&tile[r][tx * 4] = u;
  }
  __syncthreads();
#pragma unroll
  for (int j = 0; j < 4; ++j) {
    const int orow = ty + 16 * j;
    ushort4 u;
    u.x = tile[tx * 4 + 0][orow];
    u.y = tile[tx * 4 + 1][orow];
    u.z = tile[tx * 4 + 2][orow];
    u.w = tile[tx * 4 + 3][orow];
    *(ushort4*)&bt[(size_t)(o0 + orow) * D_DIM + d0 + tx * 4] = u;
  }
}

__global__ void k_cvt(const float* __restrict__ x, unsigned short* __restrict__ xb) {
  const size_t i = ((size_t)blockIdx.x * 256 + threadIdx.x) * 8;
  const float4 a = *(const float4*)&x[i];
  const float4 b = *(const float4*)&x[i + 4];
  uint4 o;
  o.x = (uint32_t)f2bf(a.x) | ((uint32_t)f2bf(a.y) << 16);
  o.y = (uint32_t)f2bf(a.z) | ((uint32_t)f2bf(a.w) << 16);
  o.z = (uint32_t)f2bf(b.x) | ((uint32_t)f2bf(b.y) << 16);
  o.w = (uint32_t)f2bf(b.z) | ((uint32_t)f2bf(b.w) << 16);
  *(uint4*)&xb[i] = o;
}

// ---------- 256x256 uniform-8-phase GEMM, 32x32x16 MFMA ----------
// C[m][n] = (sum_k A[m][k]*Bt[n][k]) * scale[n] + bias[n]
// BM=BN=256, BK=64, 512 thr = 8 waves (2Mx4N), per-wave C = 128x64 (4x2 of 32x32).
// LDS 128KB: A = [buf2][kh2][256 rows][32 k] bf16 (16KB units); B same at +64KB.
// Swizzle: local granule gl at row holds global granule g = gl ^ ((row>>1)&3);
// staged via pre-swizzled GLOBAL addr (gld_lds dest linear). Read slot spread:
// 8 slots x 2 lanes per 16-lane group (same class as round-2 measured-zero).
// Phase = one 16-k chunk c: {6 ds_read_b128, 2 gld16, BAR, lgkm0, 8 MFMA, [VMW], BAR}.
// Stage flow gives uniform vmcnt(8) waits with 4-5 phase latency margin.

#define BAR() __builtin_amdgcn_s_barrier()
#define LGKM0()                                         \
  do {                                                  \
    asm volatile("s_waitcnt lgkmcnt(0)" ::: "memory");  \
    __builtin_amdgcn_sched_barrier(0);                  \
  } while (0)
#define VMW(n) asm volatile("s_waitcnt vmcnt(" #n ")" ::: "memory")

#define STAGE_A(d, kh, ktv)                                                  \
  do {                                                                       \
    gld16(pA0 + (ktv)*64 + (kh)*32, smem + (d)*32768 + (kh)*16384 + t * 16); \
    gld16(pA1 + (ktv)*64 + (kh)*32,                                          \
          smem + (d)*32768 + (kh)*16384 + 8192 + t * 16);                    \
  } while (0)
#define STAGE_B(d, kh, ktv)                                                  \
  do {                                                                       \
    gld16(pB0 + (ktv)*64 + (kh)*32,                                          \
          smem + 65536 + (d)*32768 + (kh)*16384 + t * 16);                   \
    gld16(pB1 + (ktv)*64 + (kh)*32,                                          \
          smem + 65536 + (d)*32768 + (kh)*16384 + 8192 + t * 16);            \
  } while (0)

#define PHASE(d, c, STG, WT)                                                  \
  do {                                                                        \
    const int axo = (aBase ^ (((c)&1) * 32)) + ((c) >> 1) * 16384 + (d)*32768;\
    const int bxo = (bBase ^ (((c)&1) * 32)) + ((c) >> 1) * 16384 + (d)*32768;\
    bf16x8 aq[4], bq[2];                                                      \
    _Pragma("unroll") for (int m = 0; m < 4; ++m)                             \
        aq[m] = *(const bf16x8*)(smem + axo + m * 2048);                      \
    _Pragma("unroll") for (int n = 0; n < 2; ++n)                             \
        bq[n] = *(const bf16x8*)(smem + bxo + n * 2048);                      \
    STG;                                                                      \
    BAR();                                                                    \
    LGKM0();                                                                  \
    __builtin_amdgcn_s_setprio(1);                                            \
    _Pragma("unroll") for (int m = 0; m < 4; ++m)                             \
    _Pragma("unroll") for (int n = 0; n < 2; ++n)                             \
        acc[m][n] = __builtin_amdgcn_mfma_f32_32x32x16_bf16(                  \
            aq[m], bq[n], acc[m][n], 0, 0, 0);                                \
    __builtin_amdgcn_s_setprio(0);                                            \
    WT;                                                                       \
    BAR();                                                                    \
  } while (0)

__global__ __launch_bounds__(512, 2) void k_gemm8(
    const unsigned short* __restrict__ A,   // [M][K] bf16 bits
    const unsigned short* __restrict__ B,   // [N][K] bf16 bits (ternary)
    const float* __restrict__ scale, const float* __restrict__ bias,
    float* __restrict__ C) {
  __shared__ __align__(16) char smem[131072];

  const int bid = blockIdx.x;
  const int wg = (bid & 7) * 128 + (bid >> 3);  // XCD swizzle, 1024%8==0
  const int mb = wg >> 4, nb = wg & 15;         // 64 x 16 blocks
  const int mBase = mb * 256, nBase = nb * 256;

  const int t = threadIdx.x;
  const int lane = t & 63, wid = t >> 6;
  const int wr = wid >> 2, wc = wid & 3;  // 2 x 4 waves
  const int l31 = lane & 31, lhi = lane >> 5;
  const int swz = (lane >> 1) & 3;

  // per-lane LDS read bases (granule g' = g ^ ((row>>1)&3); row bits 1-2 = lane bits 1-2)
  const int aBase = (wr * 128 + l31) * 64 + ((lhi ^ swz) << 4);
  const int bBase = 65536 + (wc * 64 + l31) * 64 + ((lhi ^ swz) << 4);

  // staging: thread t handles LDS granules q0=t, q1=512+t of each 16KB half-tile
  // LDS granule q (row=q>>2, gl=q&3) holds global granule g = gl ^ ((q>>3)&3)
  const int q1 = 512 + t;
  const int r0 = t >> 2, g0 = (t & 3) ^ ((t >> 3) & 3);
  const int r1 = q1 >> 2, g1 = (q1 & 3) ^ ((q1 >> 3) & 3);

  const unsigned short* pA0 = A + (size_t)(mBase + r0) * D_DIM + g0 * 8;
  const unsigned short* pA1 = A + (size_t)(mBase + r1) * D_DIM + g1 * 8;
  const unsigned short* pB0 = B + (size_t)(nBase + r0) * D_DIM + g0 * 8;
  const unsigned short* pB1 = B + (size_t)(nBase + r1) * D_DIM + g1 * 8;

  f32x16 acc[4][2] = {};

  // prologue: A/B(0).kh0, A/B(0).kh1, A/B(1).kh0  (12 ops)
  STAGE_A(0, 0, 0); STAGE_B(0, 0, 0);
  STAGE_A(0, 1, 0); STAGE_B(0, 1, 0);
  STAGE_A(1, 0, 1); STAGE_B(1, 0, 1);
  VMW(8);  // first 4 ops (tile0 kh0) landed
  BAR();

  // steady state: reads at phase p use stages issued 5-6 phases earlier;
  // VMW(8) at odd-phase ends == "everything older than 4 phases landed".
  for (int I = 0; I < 31; ++I) {
    const int kt = 2 * I;
    PHASE(0, 0, STAGE_A(1, 1, kt + 1), (void)0);
    PHASE(0, 1, STAGE_B(1, 1, kt + 1), VMW(8));
    PHASE(0, 2, STAGE_A(0, 0, kt + 2), (void)0);
    PHASE(0, 3, STAGE_B(0, 0, kt + 2), VMW(8));
    PHASE(1, 0, STAGE_A(0, 1, kt + 2), (void)0);
    PHASE(1, 1, STAGE_B(0, 1, kt + 2), VMW(8));
    PHASE(1, 2, STAGE_A(1, 0, kt + 3), (void)0);
    PHASE(1, 3, STAGE_B(1, 0, kt + 3), VMW(8));
  }
  // peeled last iteration: kt = 62, 63; drain 8 -> 4 -> 0
  PHASE(0, 0, STAGE_A(1, 1, 63), (void)0);
  PHASE(0, 1, STAGE_B(1, 1, 63), VMW(8));
  PHASE(0, 2, (void)0, (void)0);
  PHASE(0, 3, (void)0, VMW(4));
  PHASE(1, 0, (void)0, (void)0);
  PHASE(1, 1, (void)0, VMW(0));
  PHASE(1, 2, (void)0, (void)0);
  PHASE(1, 3, (void)0, (void)0);

  // epilogue: 32x32 C/D mapping col=lane&31, row=(r&3)+8*(r>>2)+4*(lane>>5)
#pragma unroll
  for (int n = 0; n < 2; ++n) {
    const int gc = nBase + wc * 64 + n * 32 + l31;
    const float sc = scale[gc];
    const float bb = bias[gc];
#pragma unroll
    for (int m = 0; m < 4; ++m) {
      const int grb = mBase + wr * 128 + m * 32 + 4 * lhi;
#pragma unroll
      for (int r = 0; r < 16; ++r) {
        const int grow = grb + (r & 3) + 8 * (r >> 2);
        C[(size_t)grow * O_DIM + gc] = acc[m][n][r] * sc + bb;
      }
    }
  }
}

// ---------- launch ----------

extern "C" void kernel_launch(void* const* d_in, const int* in_sizes, int n_in,
                              void* d_out, int out_size, void* d_ws, size_t ws_size,
                              hipStream_t stream) {
  const float* x = (const float*)d_in[0];
  const float* w = (const float*)d_in[1];
  const float* bias = (const float*)d_in[2];
  float* out = (float*)d_out;

  const size_t XB_OFF = 0;
  const size_t BT_OFF = (size_t)M_DIM * D_DIM * 2;
  const size_t PART_OFF = BT_OFF + (size_t)O_DIM * D_DIM * 2;
  const size_t SCALE_OFF = PART_OFF + 8 * O_DIM * 4;
  const size_t NEED = SCALE_OFF + O_DIM * 4;
  if (ws_size < NEED) return;

  char* ws = (char*)d_ws;
  unsigned short* xb = (unsigned short*)(ws + XB_OFF);
  unsigned short* bt = (unsigned short*)(ws + BT_OFF);
  float* part = (float*)(ws + PART_OFF);
  float* scale = (float*)(ws + SCALE_OFF);

  k_scale_part<<<512, 256, 0, stream>>>(w, part);
  k_scale_fin<<<16, 256, 0, stream>>>(part, scale);
  k_tern_t<<<64 * 64, 256, 0, stream>>>(w, bt);
  k_cvt<<<(M_DIM * (D_DIM / 8)) / 256, 256, 0, stream>>>(x, xb);
  k_gemm8<<<1024, 512, 0, stream>>>(xb, bt, scale, bias, out);
}

// Round 4
// 545.995 us; speedup vs baseline: 1.0482x; 1.0482x over previous
//
#include <hip/hip_runtime.h>
#include <stdint.h>

typedef __bf16 bf16_t;
typedef bf16_t bf16x8 __attribute__((ext_vector_type(8)));
typedef float f32x4 __attribute__((ext_vector_type(4)));

#define D_DIM 4096   // K
#define O_DIM 4096   // N
#define M_DIM 16384  // M
#define THRESH 0.05f

// ---------- helpers ----------

__device__ __forceinline__ void gld16(const void* g, void* l) {
  __builtin_amdgcn_global_load_lds(
      (const __attribute__((address_space(1))) uint32_t*)(uintptr_t)g,
      (__attribute__((address_space(3))) uint32_t*)(uint32_t)(uintptr_t)l,
      16, 0, 0);
}

__device__ __forceinline__ unsigned short f2bf(float f) {  // RNE f32->bf16
  uint32_t u = __float_as_uint(f);
  u += 0x7FFFu + ((u >> 16) & 1u);
  return (unsigned short)(u >> 16);
}

__device__ __forceinline__ unsigned short tern(float v) {  // bf16 bits of {-1,0,+1}
  return (__builtin_fabsf(v) < THRESH) ? (unsigned short)0
         : (v > 0.f ? (unsigned short)0x3F80 : (unsigned short)0xBF80);
}

// ---------- pre-pass kernels (verified rounds 1-3) ----------

__global__ void k_scale_part(const float* __restrict__ w, float* __restrict__ part) {
  const int cg = blockIdx.x & 63;
  const int dz = blockIdx.x >> 6;
  const int tx = threadIdx.x & 63;
  const int ty = threadIdx.x >> 6;
  const int o = cg * 64 + tx;
  float s = 0.f;
  const float* p = w + (size_t)(dz * 512 + ty) * O_DIM + o;
  for (int i = 0; i < 128; ++i) {
    s += __builtin_fabsf(*p);
    p += 4 * O_DIM;
  }
  __shared__ float red[4][64];
  red[ty][tx] = s;
  __syncthreads();
  if (ty == 0) part[dz * O_DIM + o] = (red[0][tx] + red[1][tx]) + (red[2][tx] + red[3][tx]);
}

__global__ void k_scale_fin(const float* __restrict__ part, float* __restrict__ scale) {
  const int o = blockIdx.x * 256 + threadIdx.x;
  float s = 0.f;
#pragma unroll
  for (int z = 0; z < 8; ++z) s += part[z * O_DIM + o];
  scale[o] = s * (1.0f / 4096.0f);
}

__global__ void k_tern_t(const float* __restrict__ w, unsigned short* __restrict__ bt) {
  __shared__ __align__(16) unsigned short tile[64][68];
  const int ot = blockIdx.x & 63;
  const int dt = blockIdx.x >> 6;
  const int o0 = ot * 64, d0 = dt * 64;
  const int tx = threadIdx.x & 15, ty = threadIdx.x >> 4;
#pragma unroll
  for (int j = 0; j < 4; ++j) {
    const int r = ty + 16 * j;
    const float4 v = *(const float4*)&w[(size_t)(d0 + r) * O_DIM + o0 + tx * 4];
    ushort4 u;
    u.x = tern(v.x); u.y = tern(v.y); u.z = tern(v.z); u.w = tern(v.w);
    *(ushort4*)&tile[r][tx * 4] = u;
  }
  __syncthreads();
#pragma unroll
  for (int j = 0; j < 4; ++j) {
    const int orow = ty + 16 * j;
    ushort4 u;
    u.x = tile[tx * 4 + 0][orow];
    u.y = tile[tx * 4 + 1][orow];
    u.z = tile[tx * 4 + 2][orow];
    u.w = tile[tx * 4 + 3][orow];
    *(ushort4*)&bt[(size_t)(o0 + orow) * D_DIM + d0 + tx * 4] = u;
  }
}

__global__ void k_cvt(const float* __restrict__ x, unsigned short* __restrict__ xb) {
  const size_t i = ((size_t)blockIdx.x * 256 + threadIdx.x) * 8;
  const float4 a = *(const float4*)&x[i];
  const float4 b = *(const float4*)&x[i + 4];
  uint4 o;
  o.x = (uint32_t)f2bf(a.x) | ((uint32_t)f2bf(a.y) << 16);
  o.y = (uint32_t)f2bf(a.z) | ((uint32_t)f2bf(a.w) << 16);
  o.z = (uint32_t)f2bf(b.x) | ((uint32_t)f2bf(b.y) << 16);
  o.w = (uint32_t)f2bf(b.z) | ((uint32_t)f2bf(b.w) << 16);
  *(uint4*)&xb[i] = o;
}

// ---------- 256x256 GEMM, round-2 LDS image + deep-margin schedule ----------
// C[m][n] = (sum_k A[m][k]*Bt[n][k]) * scale[n] + bias[n]
// BM=BN=256, BK=64, 512 thr = 8 waves (2Mx4N), per-wave C = 128x64.
// LDS 128KB: A = [buf2][rowhalf2][128 rows][64 k] bf16; B same at +64KB.
// Image (zero-conflict, measured r2): granule (row,g) at byte row*128 + (g^(row&7))*16,
// staged via pre-swizzled GLOBAL addr, gld_lds dest linear.
// Calendar per tile T (buf d=T&1, parity pp=T&1), stages target tile T+2 (buf d):
//   p0: read aq0 (8 dsr) | stage B0(T+2) | MFMA(0,0)
//   p1: read aq1 (8)     | stage B1(T+2) | MFMA(0,1)
//   p2:                  | stage A0(T+2) | MFMA(1,0) | vmcnt(10)  (forces B(T+1))
//   p3: read bq(T+1) (8) | stage A1(T+2) | MFMA(1,1) | vmcnt(8)   (forces A(T+1))
// Margins: B 5-6 phases, A 4-5 phases. One lgkm0 per read-consuming phase.

#define BAR() __builtin_amdgcn_s_barrier()
#define LGKM0()                                         \
  do {                                                  \
    asm volatile("s_waitcnt lgkmcnt(0)" ::: "memory");  \
    __builtin_amdgcn_sched_barrier(0);                  \
  } while (0)
#define VMW(n) asm volatile("s_waitcnt vmcnt(" #n ")" ::: "memory")

#define STAGE_A(d, h, ktv)                                                   \
  do {                                                                       \
    gld16(pA##h##_0 + (ktv)*64, smem + (d)*32768 + (h)*16384 + t * 16);      \
    gld16(pA##h##_1 + (ktv)*64,                                              \
          smem + (d)*32768 + (h)*16384 + 8192 + t * 16);                     \
  } while (0)
#define STAGE_B(d, h, ktv)                                                   \
  do {                                                                       \
    gld16(pB##h##_0 + (ktv)*64,                                              \
          smem + 65536 + (d)*32768 + (h)*16384 + t * 16);                    \
    gld16(pB##h##_1 + (ktv)*64,                                              \
          smem + 65536 + (d)*32768 + (h)*16384 + 8192 + t * 16);             \
  } while (0)

#define READ_A(d, mh)                                                   \
  do {                                                                  \
    const char* ab_ = smem + (d)*32768 + wr * 16384 + (mh)*8192;        \
    _Pragma("unroll") for (int m4 = 0; m4 < 4; ++m4) {                  \
      aq[mh][0][m4] = *(const bf16x8*)(ab_ + m4 * 2048 + aLane);        \
      aq[mh][1][m4] = *(const bf16x8*)(ab_ + m4 * 2048 + (aLane ^ 64)); \
    }                                                                   \
  } while (0)

#define READ_B(db, pp)                                                       \
  do {                                                                       \
    const char* bb_ = smem + 65536 + (db)*32768 + hb * 16384 + hw8192;       \
    _Pragma("unroll") for (int nh = 0; nh < 2; ++nh)                         \
    _Pragma("unroll") for (int n2 = 0; n2 < 2; ++n2) {                       \
      bq[pp][nh][0][n2] =                                                    \
          *(const bf16x8*)(bb_ + nh * 4096 + n2 * 2048 + aLane);             \
      bq[pp][nh][1][n2] =                                                    \
          *(const bf16x8*)(bb_ + nh * 4096 + n2 * 2048 + (aLane ^ 64));      \
    }                                                                        \
  } while (0)

#define MQ(mh, nh, pp)                                                        \
  do {                                                                        \
    __builtin_amdgcn_s_setprio(1);                                            \
    _Pragma("unroll") for (int kk = 0; kk < 2; ++kk)                          \
    _Pragma("unroll") for (int m4 = 0; m4 < 4; ++m4)                          \
    _Pragma("unroll") for (int n2 = 0; n2 < 2; ++n2)                          \
        acc[(mh)*4 + m4][(nh)*2 + n2] =                                       \
            __builtin_amdgcn_mfma_f32_16x16x32_bf16(                          \
                aq[mh][kk][m4], bq[pp][nh][kk][n2],                           \
                acc[(mh)*4 + m4][(nh)*2 + n2], 0, 0, 0);                      \
    __builtin_amdgcn_s_setprio(0);                                            \
  } while (0)

#define TILE(d, pp, kv)                                                  \
  do {                                                                   \
    READ_A(d, 0); STAGE_B(d, 0, kv);                                     \
    BAR(); LGKM0(); MQ(0, 0, pp); BAR();                                 \
    READ_A(d, 1); STAGE_B(d, 1, kv);                                     \
    BAR(); LGKM0(); MQ(0, 1, pp); BAR();                                 \
    STAGE_A(d, 0, kv);                                                   \
    BAR(); __builtin_amdgcn_sched_barrier(0); MQ(1, 0, pp); VMW(10);     \
    BAR();                                                               \
    READ_B((d) ^ 1, (pp) ^ 1); STAGE_A(d, 1, kv);                        \
    BAR(); __builtin_amdgcn_sched_barrier(0); MQ(1, 1, pp); VMW(8);      \
    BAR();                                                               \
  } while (0)

__global__ __launch_bounds__(512, 2) void k_gemm8(
    const unsigned short* __restrict__ A,   // [M][K] bf16 bits
    const unsigned short* __restrict__ B,   // [N][K] bf16 bits (ternary)
    const float* __restrict__ scale, const float* __restrict__ bias,
    float* __restrict__ C) {
  __shared__ __align__(16) char smem[131072];

  const int bid = blockIdx.x;
  const int wg = (bid & 7) * 128 + (bid >> 3);  // XCD swizzle, 1024%8==0
  const int mb = wg >> 4, nb = wg & 15;         // 64 x 16 blocks
  const int mBase = mb * 256, nBase = nb * 256;

  const int t = threadIdx.x;
  const int lane = t & 63, wid = t >> 6;
  const int wr = wid >> 2, wc = wid & 3;  // 2 x 4 waves
  const int hb = wc >> 1;                 // B row-half this wave reads
  const int hw8192 = (wc & 1) * 8192;
  const int r16 = lane & 15, kq = lane >> 4;
  const int aLane = r16 * 128 + ((kq ^ (lane & 7)) << 4);

  // staging: thread t stages granules q0=t, q1=512+t of each 16KB half-tile
  const int q1 = 512 + t;
  const int sr0 = t >> 3, sg0 = (t & 7) ^ (sr0 & 7);
  const int sr1 = q1 >> 3, sg1 = (q1 & 7) ^ (sr1 & 7);

  const unsigned short* pA0_0 = A + (size_t)(mBase + sr0) * D_DIM + sg0 * 8;
  const unsigned short* pA0_1 = A + (size_t)(mBase + sr1) * D_DIM + sg1 * 8;
  const unsigned short* pA1_0 = A + (size_t)(mBase + 128 + sr0) * D_DIM + sg0 * 8;
  const unsigned short* pA1_1 = A + (size_t)(mBase + 128 + sr1) * D_DIM + sg1 * 8;
  const unsigned short* pB0_0 = B + (size_t)(nBase + sr0) * D_DIM + sg0 * 8;
  const unsigned short* pB0_1 = B + (size_t)(nBase + sr1) * D_DIM + sg1 * 8;
  const unsigned short* pB1_0 = B + (size_t)(nBase + 128 + sr0) * D_DIM + sg0 * 8;
  const unsigned short* pB1_1 = B + (size_t)(nBase + 128 + sr1) * D_DIM + sg1 * 8;

  f32x4 acc[8][4] = {};
  bf16x8 aq[2][2][4];      // [mh][kk][m4]
  bf16x8 bq[2][2][2][2];   // [parity][nh][kk][n2]

  // prologue: stage tiles 0 (buf0) and 1 (buf1) fully; force tile0; pre-read bq(0)
  STAGE_B(0, 0, 0); STAGE_B(0, 1, 0); STAGE_A(0, 0, 0); STAGE_A(0, 1, 0);
  STAGE_B(1, 0, 1); STAGE_B(1, 1, 1); STAGE_A(1, 0, 1); STAGE_A(1, 1, 1);
  VMW(8);  // tile0's 8 ops landed
  BAR();
  READ_B(0, 0);

  for (int I = 0; I < 32; ++I) {
    const int kv0 = (2 * I + 2) & 63;  // dummy wrap on last tiles (never read)
    const int kv1 = (2 * I + 3) & 63;
    TILE(0, 0, kv0);
    TILE(1, 1, kv1);
  }
  VMW(0);  // drain dummy stages before exit

  // epilogue: C/D mapping col=lane&15, row=4*(lane>>4)+r (verified r1/r2)
#pragma unroll
  for (int ni = 0; ni < 4; ++ni) {
    const int gc = nBase + wc * 64 + ni * 16 + r16;
    const float sc = scale[gc];
    const float bb = bias[gc];
#pragma unroll
    for (int mi = 0; mi < 8; ++mi) {
      const int gr0 = mBase + wr * 128 + mi * 16 + kq * 4;
#pragma unroll
      for (int r = 0; r < 4; ++r) {
        C[(size_t)(gr0 + r) * O_DIM + gc] = acc[mi][ni][r] * sc + bb;
      }
    }
  }
}

// ---------- launch ----------

extern "C" void kernel_launch(void* const* d_in, const int* in_sizes, int n_in,
                              void* d_out, int out_size, void* d_ws, size_t ws_size,
                              hipStream_t stream) {
  const float* x = (const float*)d_in[0];
  const float* w = (const float*)d_in[1];
  const float* bias = (const float*)d_in[2];
  float* out = (float*)d_out;

  const size_t XB_OFF = 0;
  const size_t BT_OFF = (size_t)M_DIM * D_DIM * 2;
  const size_t PART_OFF = BT_OFF + (size_t)O_DIM * D_DIM * 2;
  const size_t SCALE_OFF = PART_OFF + 8 * O_DIM * 4;
  const size_t NEED = SCALE_OFF + O_DIM * 4;
  if (ws_size < NEED) return;

  char* ws = (char*)d_ws;
  unsigned short* xb = (unsigned short*)(ws + XB_OFF);
  unsigned short* bt = (unsigned short*)(ws + BT_OFF);
  float* part = (float*)(ws + PART_OFF);
  float* scale = (float*)(ws + SCALE_OFF);

  k_scale_part<<<512, 256, 0, stream>>>(w, part);
  k_scale_fin<<<16, 256, 0, stream>>>(part, scale);
  k_tern_t<<<64 * 64, 256, 0, stream>>>(w, bt);
  k_cvt<<<(M_DIM * (D_DIM / 8)) / 256, 256, 0, stream>>>(x, xb);
  k_gemm8<<<1024, 512, 0, stream>>>(xb, bt, scale, bias, out);
}